// Round 9
// baseline (27.521 us; speedup 1.0000x reference)
//
#include <hip/hip_runtime.h>
#include <hip/hip_bf16.h>

#define N_X    65536
#define N_IND  1024
#define N_DESC 64
#define TILES  (N_IND / 16)       // 64 MFMA row-tiles (full z-panel)
#define WAVES  8                  // waves per block (512 threads)
#define STRIPS 2                  // 16-col strips per wave -> 256 cols/block
#define L2E    1.4426950408889634f
#define L2E2   2.8853900817779268f

typedef __attribute__((ext_vector_type(8))) short  short8;
typedef __attribute__((ext_vector_type(4))) float  f32x4;
typedef __attribute__((ext_vector_type(2))) float  f32x2;

static __device__ __forceinline__ ushort f2bf(float f) {
    union { float f; unsigned u; } a; a.f = f;
    unsigned r = a.u + 0x7FFF + ((a.u >> 16) & 1);   // RNE to bf16
    return (ushort)(r >> 16);
}
static __device__ __forceinline__ float bf2f(ushort h) {
    union { unsigned u; float f; } a; a.u = (unsigned)h << 16;
    return a.f;
}

// ---------------------------------------------------------------------------
// Single fused kernel, round-9 rebalance of round 8:
//   8 waves/block (512 thr), 2 strips/wave  -> 256 cols/block, grid=256.
// Halves the dominant per-CU LDS A-read traffic vs round 8 (each A-fragment
// pair now feeds 4 MFMAs instead of 2; 8 waves re-read the panel instead of
// 16) while keeping 2 waves/SIMD for latency hiding. Full weighted z-panel
// (128 KB, XOR-swizzled) + z2/alpha + wls staged once per block from clean
// inputs; x converted in-register exactly once chip-wide; output written
// directly (no part buffer, no reduce kernel).
// Swizzle: byte colb ^= (row&7)<<4 on BOTH write and read (rule #21).
// C/D layout: col = lane&15, row = 4*(lane>>4) + reg.
// ---------------------------------------------------------------------------
__global__ __launch_bounds__(512) void igpr_fused(
        const float* __restrict__ x, const float* __restrict__ z,
        const float* __restrict__ alpha, const float* __restrict__ ls,
        float* __restrict__ out) {
    struct SM {
        uint4 zt[N_IND * 8];   // 1024 rows * 128 B = 128 KB (swizzled)
        float z2[N_IND];       // log2e * ||zw_i||^2
        float al[N_IND];       // alpha
        float wls[N_DESC];     // exp(-ls/2)
    };
    __shared__ SM sm;          // 136.25 KB -> 1 block/CU, 8 waves (2/SIMD)

    const int tid  = threadIdx.x;
    const int lane = tid & 63;
    const int wave = tid >> 6;                 // 0..7
    const int p = lane & 15;                   // col within strip / z-row in tile
    const int g = lane >> 4;                   // k-group
    const int j0 = blockIdx.x * 256 + wave * (16 * STRIPS);

    if (tid < N_DESC) sm.wls[tid] = __expf(-0.5f * ls[tid]);
    __syncthreads();   // wls ready

    // ---- stage full z-panel into LDS (f32 -> weighted bf16, swizzled) ----
    {
        char* zbw = reinterpret_cast<char*>(sm.zt);
#pragma unroll
        for (int rb = 0; rb < 16; ++rb) {
            int lb  = rb * 512 + tid;        // 16B-output-granule index
            int row = lb >> 3, gr = lb & 7;  // z-row, granule in row
            float4 v0 = *reinterpret_cast<const float4*>(&z[row * 64 + gr * 8]);
            float4 v1 = *reinterpret_cast<const float4*>(&z[row * 64 + gr * 8 + 4]);
            float vv[8] = {v0.x, v0.y, v0.z, v0.w, v1.x, v1.y, v1.z, v1.w};
            ushort hb[8];
            float sq = 0.f;
#pragma unroll
            for (int e = 0; e < 8; ++e) {
                ushort h = f2bf(vv[e] * sm.wls[gr * 8 + e]);
                hb[e] = h;
                float vr = bf2f(h);
                sq = fmaf(vr, vr, sq);
            }
            uint4 u = make_uint4(
                (unsigned)hb[0] | ((unsigned)hb[1] << 16),
                (unsigned)hb[2] | ((unsigned)hb[3] << 16),
                (unsigned)hb[4] | ((unsigned)hb[5] << 16),
                (unsigned)hb[6] | ((unsigned)hb[7] << 16));
            int sw = row * 128 + ((gr * 16) ^ ((row & 7) << 4));
            *reinterpret_cast<uint4*>(zbw + sw) = u;
            // row-sum over the 8 granule-threads (xor partners within wave)
            sq += __shfl_xor(sq, 1);
            sq += __shfl_xor(sq, 2);
            sq += __shfl_xor(sq, 4);
            if (gr == 0) sm.z2[row] = sq * L2E;
        }
        sm.al[tid]       = alpha[tid];
        sm.al[tid + 512] = alpha[tid + 512];
    }

    // ---- B fragments (2 strips) + log2e*x_sq, overlaps staging ----
    short8 b[STRIPS][2];
    float xs2v[STRIPS];
#pragma unroll
    for (int s = 0; s < STRIPS; ++s) {
        const float* xr = x + (size_t)(j0 + s * 16 + p) * N_DESC;
        float sq = 0.f;
#pragma unroll
        for (int h = 0; h < 2; ++h) {
            float4 v0 = *reinterpret_cast<const float4*>(xr + h * 32 + g * 8);
            float4 v1 = *reinterpret_cast<const float4*>(xr + h * 32 + g * 8 + 4);
            float vv[8] = {v0.x, v0.y, v0.z, v0.w, v1.x, v1.y, v1.z, v1.w};
            short8 bb;
#pragma unroll
            for (int e = 0; e < 8; ++e) {
                ushort hh = f2bf(vv[e] * sm.wls[h * 32 + g * 8 + e]);
                bb[e] = (short)hh;
                float xv = bf2f(hh);
                sq = fmaf(xv, xv, sq);
            }
            b[s][h] = bb;
        }
        sq += __shfl_xor(sq, 16);
        sq += __shfl_xor(sq, 32);
        xs2v[s] = sq * L2E;
    }

    __syncthreads();   // z-panel ready (LDS read-only from here)

    const char* zb = reinterpret_cast<const char*>(sm.zt);
    const int rb0 = p * 128 + ((16 * g)      ^ ((p & 7) << 4));
    const int rb1 = p * 128 + ((64 + 16 * g) ^ ((p & 7) << 4));

    f32x2 accJ[STRIPS] = {{0.f, 0.f}, {0.f, 0.f}};

#pragma unroll 2
    for (int it = 0; it < TILES; ++it) {
        short8 a0 = *reinterpret_cast<const short8*>(zb + it * 2048 + rb0);
        short8 a1 = *reinterpret_cast<const short8*>(zb + it * 2048 + rb1);
        float4 z2 = *reinterpret_cast<const float4*>(&sm.z2[it * 16 + g * 4]);
        float4 a4 = *reinterpret_cast<const float4*>(&sm.al[it * 16 + g * 4]);

        f32x4 t[STRIPS];
#pragma unroll
        for (int s = 0; s < STRIPS; ++s) {
            f32x4 t0 = {0.f, 0.f, 0.f, 0.f};
            t0 = __builtin_amdgcn_mfma_f32_16x16x32_bf16(a0, b[s][0], t0, 0, 0, 0);
            t[s] = __builtin_amdgcn_mfma_f32_16x16x32_bf16(a1, b[s][1], t0, 0, 0, 0);
        }

        f32x2 z2p[2] = {{z2.x, z2.y}, {z2.z, z2.w}};
        f32x2 a4p[2] = {{a4.x, a4.y}, {a4.z, a4.w}};
#pragma unroll
        for (int s = 0; s < STRIPS; ++s) {
            f32x2 xs2p = {xs2v[s], xs2v[s]};
#pragma unroll
            for (int ep = 0; ep < 2; ++ep) {
                f32x2 dot2 = {t[s][2 * ep], t[s][2 * ep + 1]};
                f32x2 zx   = z2p[ep] + xs2p;               // v_pk_add_f32
                f32x2 arg  = dot2 * L2E2 - zx;             // contracts to pk_fma
                f32x2 pv   = {__builtin_amdgcn_exp2f(arg.x),
                              __builtin_amdgcn_exp2f(arg.y)};
                accJ[s]    = accJ[s] + a4p[ep] * pv;       // contracts to pk_fma
            }
        }
    }

#pragma unroll
    for (int s = 0; s < STRIPS; ++s) {
        float r = accJ[s].x + accJ[s].y;
        r += __shfl_xor(r, 16);
        r += __shfl_xor(r, 32);
        if (g == 0) out[j0 + s * 16 + p] = r;
    }
}

extern "C" void kernel_launch(void* const* d_in, const int* in_sizes, int n_in,
                              void* d_out, int out_size, void* d_ws, size_t ws_size,
                              hipStream_t stream) {
    const float* x     = (const float*)d_in[0];   // (65536, 64)
    const float* z     = (const float*)d_in[1];   // (1024, 64)
    const float* alpha = (const float*)d_in[2];   // (1024,)
    const float* ls    = (const float*)d_in[3];   // (64,)
    float* out = (float*)d_out;                   // (65536, 1)

    igpr_fused<<<dim3(N_X / 256), dim3(512), 0, stream>>>(x, z, alpha, ls, out);
}

// Round 10
// 26.905 us; speedup vs baseline: 1.0229x; 1.0229x over previous
//
#include <hip/hip_runtime.h>
#include <hip/hip_bf16.h>

#define N_X    65536
#define N_IND  1024
#define N_DESC 64
#define NCHUNK 2
#define CROWS  (N_IND / NCHUNK)   // 512 z-rows per chunk
#define TILES  (CROWS / 16)       // 32 MFMA row-tiles per chunk
#define L2E    1.4426950408889634f
#define L2E2   2.8853900817779268f

typedef __attribute__((ext_vector_type(8))) short  short8;
typedef __attribute__((ext_vector_type(4))) float  f32x4;
typedef __attribute__((ext_vector_type(2))) float  f32x2;

static __device__ __forceinline__ ushort f2bf(float f) {
    union { float f; unsigned u; } a; a.f = f;
    unsigned r = a.u + 0x7FFF + ((a.u >> 16) & 1);   // RNE to bf16
    return (ushort)(r >> 16);
}
static __device__ __forceinline__ float bf2f(ushort h) {
    union { unsigned u; float f; } a; a.u = (unsigned)h << 16;
    return a.f;
}

// ---------------------------------------------------------------------------
// Round 10: 16 waves/block (1024 thr, 4 waves/SIMD for TLP) x S=2 strips/wave
// = 512 x-cols/block over a 512-row half-panel (64 KB LDS, XOR-swizzled);
// grid (128, NCHUNK) = 256 blocks = 1/CU. part + reduce recombines chunks.
// OPERAND SWAP: mfma(x_frag, z_frag) -> D row = x-col (4g+reg), col = z-row
// (p). Epilogue constants (z2*L2E, alpha) become ONE float2 ds_read_b64 per
// tile (packed za[], 16x8B addrs = 32 banks, conflict-free), and the 2
// z-frag b128 reads are shared by both strips: 3 LDS instrs / tile / wave.
// A/B frag formats are symmetric (lane&15=row|col, k=(lane>>4)*8+e), so the
// swap is argument order + output reindexing only. xs2 redistributed once
// via small LDS array. Swizzle: byte colb ^= (row&7)<<4 both sides (rule 21).
// ---------------------------------------------------------------------------
__global__ __launch_bounds__(1024) void igpr_fused(
        const float* __restrict__ x, const float* __restrict__ z,
        const float* __restrict__ alpha, const float* __restrict__ ls,
        float* __restrict__ part) {
    struct SM {
        uint4  zt[CROWS * 8];    // 512 rows * 128 B = 64 KB (swizzled)
        float2 za[CROWS];        // {log2e*||zw||^2, alpha}  (4 KB)
        float  xs2a[16 * 32];    // per-wave xs2 redistribution (2 KB)
        float  wls[N_DESC];      // exp(-ls/2)
    };
    __shared__ SM sm;            // ~70.3 KB -> 1 block/CU guaranteed fit

    const int tid  = threadIdx.x;
    const int lane = tid & 63;
    const int wave = tid >> 6;                  // 0..15
    const int p = lane & 15;                    // z-row within tile (D col)
    const int g = lane >> 4;                    // k-group; D rows 4g..4g+3
    const int j0 = blockIdx.x * 512 + wave * 32;  // wave's first x-col
    const int c  = blockIdx.y;                  // z-chunk

    if (tid < N_DESC) sm.wls[tid] = __expf(-0.5f * ls[tid]);
    __syncthreads();   // wls ready

    // ---- stage half z-panel (f32 -> weighted bf16, swizzled) + za ----
    {
        const float* zc = z + (size_t)c * CROWS * N_DESC;
        char* zbw = reinterpret_cast<char*>(sm.zt);
#pragma unroll
        for (int rb = 0; rb < 4; ++rb) {
            int lb  = rb * 1024 + tid;       // 16B-granule index (4096 total)
            int row = lb >> 3, gr = lb & 7;  // local z-row, granule in row
            float4 v0 = *reinterpret_cast<const float4*>(&zc[row * 64 + gr * 8]);
            float4 v1 = *reinterpret_cast<const float4*>(&zc[row * 64 + gr * 8 + 4]);
            float vv[8] = {v0.x, v0.y, v0.z, v0.w, v1.x, v1.y, v1.z, v1.w};
            ushort hb[8];
            float sq = 0.f;
#pragma unroll
            for (int e = 0; e < 8; ++e) {
                ushort h = f2bf(vv[e] * sm.wls[gr * 8 + e]);
                hb[e] = h;
                float vr = bf2f(h);
                sq = fmaf(vr, vr, sq);
            }
            uint4 u = make_uint4(
                (unsigned)hb[0] | ((unsigned)hb[1] << 16),
                (unsigned)hb[2] | ((unsigned)hb[3] << 16),
                (unsigned)hb[4] | ((unsigned)hb[5] << 16),
                (unsigned)hb[6] | ((unsigned)hb[7] << 16));
            int sw = row * 128 + ((gr * 16) ^ ((row & 7) << 4));
            *reinterpret_cast<uint4*>(zbw + sw) = u;
            // row-sum over the 8 granule-lanes (tid bits 0..2)
            sq += __shfl_xor(sq, 1);
            sq += __shfl_xor(sq, 2);
            sq += __shfl_xor(sq, 4);
            if (gr == 0) {
                float2 zv; zv.x = sq * L2E; zv.y = alpha[c * CROWS + row];
                sm.za[row] = zv;
            }
        }
    }

    // ---- B->A fragments: 2 x-strips (x stays clean, converted in-reg) ----
    short8 b[2][2];
#pragma unroll
    for (int s = 0; s < 2; ++s) {
        const float* xr = x + (size_t)(j0 + s * 16 + p) * N_DESC;
        float sq = 0.f;
#pragma unroll
        for (int h = 0; h < 2; ++h) {
            float4 v0 = *reinterpret_cast<const float4*>(xr + h * 32 + g * 8);
            float4 v1 = *reinterpret_cast<const float4*>(xr + h * 32 + g * 8 + 4);
            float vv[8] = {v0.x, v0.y, v0.z, v0.w, v1.x, v1.y, v1.z, v1.w};
            short8 bb;
#pragma unroll
            for (int e = 0; e < 8; ++e) {
                ushort hh = f2bf(vv[e] * sm.wls[h * 32 + g * 8 + e]);
                bb[e] = (short)hh;
                float xv = bf2f(hh);
                sq = fmaf(xv, xv, sq);
            }
            b[s][h] = bb;
        }
        sq += __shfl_xor(sq, 16);   // full ||xw||^2 over k-groups
        sq += __shfl_xor(sq, 32);
        if (lane < 16) sm.xs2a[wave * 32 + s * 16 + p] = sq * L2E;
    }

    __syncthreads();   // z-panel, za, xs2a all ready (LDS read-only now)

    // xs2 for the x-cols this lane OWNS after the swap: rows 4g..4g+3 / strip
    f32x2 xs2p[2][2];
#pragma unroll
    for (int s = 0; s < 2; ++s) {
        float4 v = *reinterpret_cast<const float4*>(
            &sm.xs2a[wave * 32 + s * 16 + 4 * g]);
        f32x2 lo; lo.x = v.x; lo.y = v.y;
        f32x2 hi; hi.x = v.z; hi.y = v.w;
        xs2p[s][0] = lo; xs2p[s][1] = hi;
    }

    const char* zb = reinterpret_cast<const char*>(sm.zt);
    const int rb0 = p * 128 + ((16 * g)      ^ ((p & 7) << 4));
    const int rb1 = p * 128 + ((64 + 16 * g) ^ ((p & 7) << 4));

    f32x2 acc2[2][2] = {{{0.f, 0.f}, {0.f, 0.f}}, {{0.f, 0.f}, {0.f, 0.f}}};

#pragma unroll 2
    for (int it = 0; it < TILES; ++it) {
        short8 a0 = *reinterpret_cast<const short8*>(zb + it * 2048 + rb0);
        short8 a1 = *reinterpret_cast<const short8*>(zb + it * 2048 + rb1);
        float2 zap = sm.za[it * 16 + p];          // ds_read_b64, conflict-free
        f32x2 zsp; zsp.x = zap.x; zsp.y = zap.x;  // z2 splat
        f32x2 asp; asp.x = zap.y; asp.y = zap.y;  // alpha splat

#pragma unroll
        for (int s = 0; s < 2; ++s) {
            f32x4 t = {0.f, 0.f, 0.f, 0.f};
            t = __builtin_amdgcn_mfma_f32_16x16x32_bf16(b[s][0], a0, t, 0, 0, 0);
            t = __builtin_amdgcn_mfma_f32_16x16x32_bf16(b[s][1], a1, t, 0, 0, 0);
#pragma unroll
            for (int w = 0; w < 2; ++w) {
                f32x2 dot2; dot2.x = t[2 * w]; dot2.y = t[2 * w + 1];
                f32x2 zx  = zsp + xs2p[s][w];              // v_pk_add_f32
                f32x2 arg = dot2 * L2E2 - zx;              // pk_fma (neg mod)
                f32x2 pv; pv.x = __builtin_amdgcn_exp2f(arg.x);
                          pv.y = __builtin_amdgcn_exp2f(arg.y);
                acc2[s][w] = acc2[s][w] + asp * pv;        // pk_fma
            }
        }
    }

    // reduce over the 16 p-lanes (z-rows) and write part
    const size_t ob = (size_t)c * N_X;
#pragma unroll
    for (int s = 0; s < 2; ++s)
#pragma unroll
        for (int w = 0; w < 2; ++w)
#pragma unroll
            for (int q = 0; q < 2; ++q) {
                float r = (q == 0) ? acc2[s][w].x : acc2[s][w].y;
                r += __shfl_xor(r, 1);
                r += __shfl_xor(r, 2);
                r += __shfl_xor(r, 4);
                r += __shfl_xor(r, 8);
                if (p == 0)
                    part[ob + j0 + s * 16 + 4 * g + 2 * w + q] = r;
            }
}

// ---------------------------------------------------------------------------
// reduce: out[j] = part[0][j] + part[1][j]
// ---------------------------------------------------------------------------
__global__ void igpr_reduce(const float* __restrict__ part,
                            float* __restrict__ out) {
    int j = blockIdx.x * 256 + threadIdx.x;
    out[j] = part[j] + part[N_X + j];
}

extern "C" void kernel_launch(void* const* d_in, const int* in_sizes, int n_in,
                              void* d_out, int out_size, void* d_ws, size_t ws_size,
                              hipStream_t stream) {
    const float* x     = (const float*)d_in[0];   // (65536, 64)
    const float* z     = (const float*)d_in[1];   // (1024, 64)
    const float* alpha = (const float*)d_in[2];   // (1024,)
    const float* ls    = (const float*)d_in[3];   // (64,)
    float* out = (float*)d_out;                   // (65536, 1)

    float* part = (float*)d_ws;                   // f32[NCHUNK * N_X]

    igpr_fused<<<dim3(N_X / 512, NCHUNK), dim3(1024), 0, stream>>>(
        x, z, alpha, ls, part);
    igpr_reduce<<<dim3(N_X / 256), dim3(256), 0, stream>>>(part, out);
}